// Round 8
// baseline (295.777 us; speedup 1.0000x reference)
//
#include <hip/hip_runtime.h>

// ---------------------------------------------------------------------------
// G_CAM_Module: out = gamma * (GA @ x) + x, where GA comes from a chain of
// softmaxed 64x64 Gram matrices of x and g.
//
//   A) gram_kernel  : partial Grams via MFMA f16. Staging via
//                     global_load_lds (width=16, zero data VGPRs), f32 LDS
//                     tiles with source-side XOR swizzle, 2-phase dbuf,
//                     one barrier per pass. cvt f32->f16 at consume.
//   B) reduce_kernel: sum 64 chunk-partials -> ex[b], eg[b]
//   C) chain_kernel : softmax chain -> M = gamma*GA   (no identity; tiny fp32)
//   D) apply_kernel : out[b] = M[b] @ x_b + x_b via MFMA f16 (fp32 residual)
// ---------------------------------------------------------------------------

typedef _Float16 h8 __attribute__((ext_vector_type(8)));
typedef float    f4 __attribute__((ext_vector_type(4)));
typedef __fp16   p2 __attribute__((ext_vector_type(2)));   // cvt_pkrtz result
typedef unsigned int u4v __attribute__((ext_vector_type(4)));

#define NB 16
#define NC 64
#define NPIX 65536
#define GRAM_CHUNK 1024                 // pixels per gram block
#define PASS_PX 64                      // pixels per LDS pass (f32)
#define NPASS (GRAM_CHUNK / PASS_PX)    // 16
#define NCHUNK (NPIX / GRAM_CHUNK)      // 64
#define TILE_B 16384                    // one 64x64 f32 tile, bytes
#define BUF_B  (2 * TILE_B)             // x + g tiles per buffer

#define AP_NPX 256                      // apply: pixels per block
#define XT_ROW 72                       // apply: xT row stride in halves (144B)

__device__ __forceinline__ unsigned int pk(float a, float b) {
    p2 v = __builtin_amdgcn_cvt_pkrtz(a, b);
    return __builtin_bit_cast(unsigned int, v);
}

__device__ __forceinline__ void g2lds16(const void* g, void* l) {
    __builtin_amdgcn_global_load_lds(
        (const __attribute__((address_space(1))) void*)g,
        (__attribute__((address_space(3))) void*)l, 16, 0, 0);
}

// ---- Kernel A: partial Gram matrices via MFMA + global_load_lds -----------
// grid (64, 16), 512 threads = 8 waves. Waves 0-3: x-gram row-blocks 0-3;
// waves 4-7: g-gram. LDS layout (per buffer): x tile then g tile, each
// [64 rows][64 px f32], row-linear, quad index XOR-swizzled with (row&7).
// global_load_lds dest is linear (wave base + lane*16); the swizzle is
// applied on the per-lane GLOBAL source (rule: linear dest + inv-swz source
// + swz on read).
__global__ __launch_bounds__(512, 2) void gram_kernel(
    const float* __restrict__ x, const float* __restrict__ g,
    float* __restrict__ part)
{
    __shared__ __align__(16) char lds[2][BUF_B];   // 64 KB

    const int tid = threadIdx.x;
    const int b = blockIdx.y;
    const size_t cbase = (size_t)b * NC * NPIX + (size_t)blockIdx.x * GRAM_CHUNK;

    const int w     = tid >> 6;
    const int lane  = tid & 63;
    const int mtx   = w >> 2;         // 0: x, 1: g (consume role)
    const int rb    = w & 3;          // C row-block (16 rows)
    const int l15   = lane & 15;
    const int khalf = lane >> 4;      // 0..3 -> 8-elem k-group

    // ---- staging source pointers: 4 load-instrs per thread per pass ----
    // dest byte D = i*8192 + tid*16 in the 32KB buffer; decode row/quad,
    // inverse-swizzle the quad for the global source.
    const float* srcp[4];
    #pragma unroll
    for (int i = 0; i < 4; ++i) {
        int D    = i * 8192 + tid * 16;
        int row  = D >> 8;            // 0..127 (0-63 x, 64-127 g)
        int r    = row & 63;
        int qsrc = ((D >> 4) & 15) ^ (r & 7);
        const float* basep = (row >> 6) ? g : x;
        srcp[i] = basep + cbase + (size_t)r * NPIX + qsrc * 4;
    }

    f4 acc[4];
    #pragma unroll
    for (int cb = 0; cb < 4; ++cb) acc[cb] = (f4){0.f, 0.f, 0.f, 0.f};

    // issue one pass's 4 global_load_lds and advance sources
    auto stage = [&](char* buf) {
        #pragma unroll
        for (int i = 0; i < 4; ++i) {
            g2lds16(srcp[i], buf + i * 8192 + w * 1024);
            srcp[i] += PASS_PX;
        }
    };

    // read one 8-f32 fragment (row r, quad q0..q0+1) from tile, cvt to h8
    auto frag = [&](const char* tile, int r, int q0) -> h8 {
        const char* p = tile + (r << 8);
        f4 lo = *(const f4*)(p + ((q0 ^ (r & 7)) << 4));
        f4 hi = *(const f4*)(p + (((q0 + 1) ^ (r & 7)) << 4));
        u4v u;
        u.x = pk(lo.x, lo.y); u.y = pk(lo.z, lo.w);
        u.z = pk(hi.x, hi.y); u.w = pk(hi.z, hi.w);
        return __builtin_bit_cast(h8, u);
    };

    stage(lds[0]);
    __syncthreads();                       // pass 0 data visible

    for (int t = 0; t < NPASS; ++t) {
        if (t + 1 < NPASS) stage(lds[(t + 1) & 1]);   // issue next pass

        const char* tile = lds[t & 1] + mtx * TILE_B;
        #pragma unroll
        for (int kc = 0; kc < 2; ++kc) {               // K=32 chunks
            int q0 = kc * 8 + khalf * 2;
            h8 a = frag(tile, rb * 16 + l15, q0);
            #pragma unroll
            for (int cb = 0; cb < 4; ++cb) {
                h8 bf = frag(tile, cb * 16 + l15, q0);
                acc[cb] = __builtin_amdgcn_mfma_f32_16x16x32_f16(a, bf, acc[cb], 0, 0, 0);
            }
        }
        __syncthreads();   // drains next-pass loads (vmcnt0) + consume done
    }

    float* po = part + (((size_t)blockIdx.x * NB + b) * 2 + mtx) * 4096;
    #pragma unroll
    for (int cb = 0; cb < 4; ++cb)
        #pragma unroll
        for (int r = 0; r < 4; ++r)
            po[(rb * 16 + khalf * 4 + r) * 64 + cb * 16 + l15] = acc[cb][r];
}

// ---- Kernel B: reduce 64 chunk-partials -> ex, eg -------------------------
__global__ __launch_bounds__(256) void reduce_kernel(
    const float* __restrict__ part, float* __restrict__ ex, float* __restrict__ eg)
{
    const int idx = blockIdx.x * 256 + threadIdx.x;
    const int bm = idx >> 12;          // b*2 + m
    const int cd = idx & 4095;
    float s = 0.f;
    #pragma unroll 8
    for (int ch = 0; ch < NCHUNK; ++ch)
        s += part[(size_t)ch * (NB * 2 * 4096) + (size_t)bm * 4096 + cd];
    float* dst = (bm & 1) ? eg : ex;
    dst[(bm >> 1) * 4096 + cd] = s;
}

// ---- Kernel C: softmax chain -> M = gamma*GA (no identity) ----------------
__global__ __launch_bounds__(256) void chain_kernel(
    const float* __restrict__ ex, const float* __restrict__ eg,
    const float* __restrict__ gammap, float* __restrict__ M)
{
    __shared__ float A1[64][68];
    __shared__ float A2[64][68];
    __shared__ float red[64][4];

    const int b = blockIdx.x;
    const int tid = threadIdx.x;

    if (tid < 64) {
        const int c = tid;
        float r[64];
        #pragma unroll
        for (int d = 0; d < 64; ++d) r[d] = ex[b * 4096 + c * 64 + d];
        float mx = r[0];
        #pragma unroll
        for (int d = 1; d < 64; ++d) mx = fmaxf(mx, r[d]);
        float s = 0.f;
        #pragma unroll
        for (int d = 0; d < 64; ++d) { r[d] = expf(r[d] - mx); s += r[d]; }
        float inv = 1.f / s;
        #pragma unroll
        for (int d = 0; d < 64; ++d) A1[c][d] = r[d] * inv;

        #pragma unroll
        for (int d = 0; d < 64; ++d) r[d] = eg[b * 4096 + c * 64 + d];
        mx = r[0];
        #pragma unroll
        for (int d = 1; d < 64; ++d) mx = fmaxf(mx, r[d]);
        s = 0.f;
        #pragma unroll
        for (int d = 0; d < 64; ++d) { r[d] = expf(r[d] - mx); s += r[d]; }
        inv = 1.f / s;
        #pragma unroll
        for (int d = 0; d < 64; ++d) A2[c][d] = r[d] * inv;
    }
    __syncthreads();

    const int c = tid >> 2, sq = tid & 3;
    float ge[16];
    #pragma unroll
    for (int k = 0; k < 16; ++k) ge[k] = 0.f;
    for (int d = 0; d < 64; ++d) {
        float a = A1[c][d];
        const float* row = &A2[d][sq * 16];
        #pragma unroll
        for (int k = 0; k < 16; ++k) ge[k] = fmaf(a, row[k], ge[k]);
    }

    float mx = ge[0];
    #pragma unroll
    for (int k = 1; k < 16; ++k) mx = fmaxf(mx, ge[k]);
    red[c][sq] = mx;
    __syncthreads();
    float gm = fmaxf(fmaxf(red[c][0], red[c][1]), fmaxf(red[c][2], red[c][3]));
    __syncthreads();

    float gen[16];
    #pragma unroll
    for (int k = 0; k < 16; ++k) gen[k] = gm - ge[k];
    float mx2 = gen[0];
    #pragma unroll
    for (int k = 1; k < 16; ++k) mx2 = fmaxf(mx2, gen[k]);
    red[c][sq] = mx2;
    __syncthreads();
    float m2 = fmaxf(fmaxf(red[c][0], red[c][1]), fmaxf(red[c][2], red[c][3]));
    __syncthreads();

    float p[16];
    float s = 0.f;
    #pragma unroll
    for (int k = 0; k < 16; ++k) { p[k] = expf(gen[k] - m2); s += p[k]; }
    red[c][sq] = s;
    __syncthreads();
    float S = red[c][0] + red[c][1] + red[c][2] + red[c][3];

    float gam = gammap[0];
    float invS = 1.f / S;
    #pragma unroll
    for (int k = 0; k < 16; ++k) {
        int e = sq * 16 + k;
        M[b * 4096 + c * 64 + e] = gam * p[k] * invS;   // NO +I: residual in apply
    }
}

// ---- Kernel D: out[b] = M[b] @ x[b] + x[b] via MFMA ------------------------
__global__ __launch_bounds__(256) void apply_kernel(
    const float* __restrict__ x, const float* __restrict__ M,
    float* __restrict__ out)
{
    __shared__ __align__(16) _Float16 xT[AP_NPX * XT_ROW];   // 36864 B
    __shared__ __align__(16) _Float16 Ml[64 * XT_ROW];       //  9216 B

    const int tid = threadIdx.x;
    const int b = blockIdx.y;
    const int n0 = blockIdx.x * AP_NPX;
    const float* xb = x + (size_t)b * NC * NPIX + n0;

    #pragma unroll
    for (int it = 0; it < 8; ++it) {
        int e = it * 256 + tid;
        int q  = e & 63;          // f4 col (4 pixels)
        int dp = e >> 6;          // d-pair 0..31
        f4 va = *(const f4*)(xb + (size_t)(2 * dp)     * NPIX + q * 4);
        f4 vb = *(const f4*)(xb + (size_t)(2 * dp + 1) * NPIX + q * 4);
        #pragma unroll
        for (int j = 0; j < 4; ++j) {
            float aj = (j == 0) ? va.x : (j == 1) ? va.y : (j == 2) ? va.z : va.w;
            float bj = (j == 0) ? vb.x : (j == 1) ? vb.y : (j == 2) ? vb.z : vb.w;
            *reinterpret_cast<unsigned int*>(&xT[(q * 4 + j) * XT_ROW + 2 * dp]) = pk(aj, bj);
        }
    }
    const float* Mb = M + b * 4096;
    #pragma unroll
    for (int it = 0; it < 4; ++it) {
        int e = it * 256 + tid;
        int c  = e >> 4;
        int qq = e & 15;
        f4 mv = *(const f4*)(Mb + c * 64 + qq * 4);
        *reinterpret_cast<unsigned int*>(&Ml[c * XT_ROW + qq * 4])     = pk(mv.x, mv.y);
        *reinterpret_cast<unsigned int*>(&Ml[c * XT_ROW + qq * 4 + 2]) = pk(mv.z, mv.w);
    }
    __syncthreads();

    const int w    = tid >> 6;
    const int lane = tid & 63;
    const int l15  = lane & 15;
    const int kh   = lane >> 4;

    h8 bfrag[4][2];
    #pragma unroll
    for (int nb = 0; nb < 4; ++nb)
        #pragma unroll
        for (int ks = 0; ks < 2; ++ks)
            bfrag[nb][ks] = *reinterpret_cast<const h8*>(
                &xT[(w * 64 + nb * 16 + l15) * XT_ROW + ks * 32 + kh * 8]);

    f4 acc[4][4];   // [cb][nb]
    #pragma unroll
    for (int cb = 0; cb < 4; ++cb)
        #pragma unroll
        for (int nb = 0; nb < 4; ++nb) acc[cb][nb] = (f4){0.f, 0.f, 0.f, 0.f};

    #pragma unroll
    for (int cb = 0; cb < 4; ++cb) {
        #pragma unroll
        for (int ks = 0; ks < 2; ++ks) {
            h8 a = *reinterpret_cast<const h8*>(
                &Ml[(cb * 16 + l15) * XT_ROW + ks * 32 + kh * 8]);
            #pragma unroll
            for (int nb = 0; nb < 4; ++nb)
                acc[cb][nb] = __builtin_amdgcn_mfma_f32_16x16x32_f16(a, bfrag[nb][ks], acc[cb][nb], 0, 0, 0);
        }
    }

    const size_t base = (size_t)b * NC * NPIX + n0 + w * 64;
    #pragma unroll
    for (int cb = 0; cb < 4; ++cb) {
        #pragma unroll
        for (int r = 0; r < 4; ++r) {
            const int row = cb * 16 + kh * 4 + r;
            #pragma unroll
            for (int nb = 0; nb < 4; ++nb) {
                size_t idx = base + (size_t)row * NPIX + nb * 16 + l15;
                out[idx] = acc[cb][nb][r] + x[idx];
            }
        }
    }
}

extern "C" void kernel_launch(void* const* d_in, const int* in_sizes, int n_in,
                              void* d_out, int out_size, void* d_ws, size_t ws_size,
                              hipStream_t stream) {
    const float* x     = (const float*)d_in[0];
    const float* g     = (const float*)d_in[1];
    const float* gamma = (const float*)d_in[2];
    float* out = (float*)d_out;
    float* ws  = (float*)d_ws;

    float* ex = ws;                  // 16*4096 floats
    float* eg = ws + NB * 4096;      // 16*4096 floats
    float* M  = ws + 2 * NB * 4096;  // 16*4096 floats

    // d_out doubles as scratch for the 33.5 MB gram partials; apply_kernel
    // fully overwrites d_out afterwards (stream-ordered), so this is safe.
    float* part = out;

    gram_kernel<<<dim3(NCHUNK, NB), 512, 0, stream>>>(x, g, part);
    reduce_kernel<<<512, 256, 0, stream>>>(part, ex, eg);
    chain_kernel<<<NB, 256, 0, stream>>>(ex, eg, gamma, M);
    apply_kernel<<<dim3(NPIX / AP_NPX, NB), 256, 0, stream>>>(x, M, out);
}

// Round 9
// 282.810 us; speedup vs baseline: 1.0458x; 1.0458x over previous
//
#include <hip/hip_runtime.h>

// ---------------------------------------------------------------------------
// G_CAM_Module: out = gamma * (GA @ x) + x, where GA comes from a chain of
// softmaxed 64x64 Gram matrices of x and g.
//
//   A) gram_kernel  : partial Grams via MFMA f16, "apply-shaped": one matrix
//                     per block, small LDS (17.5 KB), 2048 blocks -> 8
//                     blocks/CU resident; TLP (not ILP) hides latency.
//   B) reduce_kernel: sum 64 chunk-partials -> ex[b], eg[b]
//   C) chain_kernel : softmax chain -> M = gamma*GA   (no identity; tiny fp32)
//   D) apply_kernel : out[b] = M[b] @ x_b + x_b via MFMA f16 (fp32 residual)
// ---------------------------------------------------------------------------

typedef _Float16 h8 __attribute__((ext_vector_type(8)));
typedef float    f4 __attribute__((ext_vector_type(4)));
typedef __fp16   p2 __attribute__((ext_vector_type(2)));   // cvt_pkrtz result
typedef unsigned long long ull;

#define NB 16
#define NC 64
#define NPIX 65536
#define GRAM_CHUNK 1024                 // pixels per gram block
#define PASS_PX 128                     // pixels per LDS pass
#define NPASS (GRAM_CHUNK / PASS_PX)    // 8
#define NCHUNK (NPIX / GRAM_CHUNK)      // 64
#define ROW_H 136                       // LDS row stride, halves (272 B)
#define LDS_H (64 * ROW_H + 64)         // halves incl. 8-row group pads

#define AP_NPX 256                      // apply: pixels per block
#define XT_ROW 72                       // apply: xT row stride in halves (144B)

__device__ __forceinline__ int rowbase_h(int c) {
    return c * ROW_H + (c >> 3) * 8;
}

__device__ __forceinline__ unsigned int pk(float a, float b) {
    p2 v = __builtin_amdgcn_cvt_pkrtz(a, b);
    return __builtin_bit_cast(unsigned int, v);
}

// ---- Kernel A: partial Gram matrices via MFMA, one matrix per block -------
// grid (64, 16, 2): chunk, batch, which-matrix. 256 threads = 4 waves; wave w
// computes the 16x64 slab rows [16w, 16w+16). Single small LDS buffer ->
// 8 blocks/CU resident; latency hidden by thread-level parallelism.
__global__ __launch_bounds__(256, 6) void gram_kernel(
    const float* __restrict__ x, const float* __restrict__ g,
    float* __restrict__ part)
{
    __shared__ __align__(16) _Float16 buf[LDS_H];   // 17.5 KB

    const int tid = threadIdx.x;
    const int mtx = blockIdx.z;
    const float* src = (mtx ? g : x)
        + (size_t)blockIdx.y * NC * NPIX + (size_t)blockIdx.x * GRAM_CHUNK;

    const int w     = tid >> 6;
    const int lane  = tid & 63;
    const int l15   = lane & 15;
    const int khalf = lane >> 4;      // 0..3 -> 8-elem k-group
    const int abase_h = rowbase_h(w * 16 + l15);

    // staging coords: e = it*256+tid; q = quad within 128 px; r = channel row
    const int sq = tid & 31;
    const int sr = tid >> 5;          // +8 rows per it

    f4 acc[4];
    #pragma unroll
    for (int cb = 0; cb < 4; ++cb) acc[cb] = (f4){0.f, 0.f, 0.f, 0.f};

    for (int pass = 0; pass < NPASS; ++pass) {
        const float* ps = src + pass * PASS_PX;
        // ---- stage 64ch x 128px as f16 (8 independent f4 loads) ----
        #pragma unroll
        for (int it = 0; it < 8; ++it) {
            int r = it * 8 + sr;
            f4 v = *(const f4*)(ps + (size_t)r * NPIX + sq * 4);
            ull h = (ull)pk(v.x, v.y) | ((ull)pk(v.z, v.w) << 32);
            *reinterpret_cast<ull*>(&buf[rowbase_h(r) + 4 * sq]) = h;
        }
        __syncthreads();

        // ---- consume: 4 K-steps x (1 A-frag + 4 B-frags + 4 MFMA) ----
        #pragma unroll
        for (int ks = 0; ks < 4; ++ks) {
            int koff = ks * 32 + khalf * 8;
            h8 a = *reinterpret_cast<const h8*>(&buf[abase_h + koff]);
            #pragma unroll
            for (int cb = 0; cb < 4; ++cb) {
                h8 bf = *reinterpret_cast<const h8*>(&buf[rowbase_h(cb * 16 + l15) + koff]);
                acc[cb] = __builtin_amdgcn_mfma_f32_16x16x32_f16(a, bf, acc[cb], 0, 0, 0);
            }
        }
        __syncthreads();
    }

    float* po = part + (((size_t)blockIdx.x * NB + blockIdx.y) * 2 + mtx) * 4096;
    #pragma unroll
    for (int cb = 0; cb < 4; ++cb)
        #pragma unroll
        for (int r = 0; r < 4; ++r)
            po[(w * 16 + khalf * 4 + r) * 64 + cb * 16 + l15] = acc[cb][r];
}

// ---- Kernel B: reduce 64 chunk-partials -> ex, eg -------------------------
__global__ __launch_bounds__(256) void reduce_kernel(
    const float* __restrict__ part, float* __restrict__ ex, float* __restrict__ eg)
{
    const int idx = blockIdx.x * 256 + threadIdx.x;
    const int bm = idx >> 12;          // b*2 + m
    const int cd = idx & 4095;
    float s = 0.f;
    #pragma unroll 8
    for (int ch = 0; ch < NCHUNK; ++ch)
        s += part[(size_t)ch * (NB * 2 * 4096) + (size_t)bm * 4096 + cd];
    float* dst = (bm & 1) ? eg : ex;
    dst[(bm >> 1) * 4096 + cd] = s;
}

// ---- Kernel C: softmax chain -> M = gamma*GA (no identity) ----------------
__global__ __launch_bounds__(256) void chain_kernel(
    const float* __restrict__ ex, const float* __restrict__ eg,
    const float* __restrict__ gammap, float* __restrict__ M)
{
    __shared__ float A1[64][68];
    __shared__ float A2[64][68];
    __shared__ float red[64][4];

    const int b = blockIdx.x;
    const int tid = threadIdx.x;

    if (tid < 64) {
        const int c = tid;
        float r[64];
        #pragma unroll
        for (int d = 0; d < 64; ++d) r[d] = ex[b * 4096 + c * 64 + d];
        float mx = r[0];
        #pragma unroll
        for (int d = 1; d < 64; ++d) mx = fmaxf(mx, r[d]);
        float s = 0.f;
        #pragma unroll
        for (int d = 0; d < 64; ++d) { r[d] = expf(r[d] - mx); s += r[d]; }
        float inv = 1.f / s;
        #pragma unroll
        for (int d = 0; d < 64; ++d) A1[c][d] = r[d] * inv;

        #pragma unroll
        for (int d = 0; d < 64; ++d) r[d] = eg[b * 4096 + c * 64 + d];
        mx = r[0];
        #pragma unroll
        for (int d = 1; d < 64; ++d) mx = fmaxf(mx, r[d]);
        s = 0.f;
        #pragma unroll
        for (int d = 0; d < 64; ++d) { r[d] = expf(r[d] - mx); s += r[d]; }
        inv = 1.f / s;
        #pragma unroll
        for (int d = 0; d < 64; ++d) A2[c][d] = r[d] * inv;
    }
    __syncthreads();

    const int c = tid >> 2, sq = tid & 3;
    float ge[16];
    #pragma unroll
    for (int k = 0; k < 16; ++k) ge[k] = 0.f;
    for (int d = 0; d < 64; ++d) {
        float a = A1[c][d];
        const float* row = &A2[d][sq * 16];
        #pragma unroll
        for (int k = 0; k < 16; ++k) ge[k] = fmaf(a, row[k], ge[k]);
    }

    float mx = ge[0];
    #pragma unroll
    for (int k = 1; k < 16; ++k) mx = fmaxf(mx, ge[k]);
    red[c][sq] = mx;
    __syncthreads();
    float gm = fmaxf(fmaxf(red[c][0], red[c][1]), fmaxf(red[c][2], red[c][3]));
    __syncthreads();

    float gen[16];
    #pragma unroll
    for (int k = 0; k < 16; ++k) gen[k] = gm - ge[k];
    float mx2 = gen[0];
    #pragma unroll
    for (int k = 1; k < 16; ++k) mx2 = fmaxf(mx2, gen[k]);
    red[c][sq] = mx2;
    __syncthreads();
    float m2 = fmaxf(fmaxf(red[c][0], red[c][1]), fmaxf(red[c][2], red[c][3]));
    __syncthreads();

    float p[16];
    float s = 0.f;
    #pragma unroll
    for (int k = 0; k < 16; ++k) { p[k] = expf(gen[k] - m2); s += p[k]; }
    red[c][sq] = s;
    __syncthreads();
    float S = red[c][0] + red[c][1] + red[c][2] + red[c][3];

    float gam = gammap[0];
    float invS = 1.f / S;
    #pragma unroll
    for (int k = 0; k < 16; ++k) {
        int e = sq * 16 + k;
        M[b * 4096 + c * 64 + e] = gam * p[k] * invS;   // NO +I: residual in apply
    }
}

// ---- Kernel D: out[b] = M[b] @ x[b] + x[b] via MFMA ------------------------
__global__ __launch_bounds__(256) void apply_kernel(
    const float* __restrict__ x, const float* __restrict__ M,
    float* __restrict__ out)
{
    __shared__ __align__(16) _Float16 xT[AP_NPX * XT_ROW];   // 36864 B
    __shared__ __align__(16) _Float16 Ml[64 * XT_ROW];       //  9216 B

    const int tid = threadIdx.x;
    const int b = blockIdx.y;
    const int n0 = blockIdx.x * AP_NPX;
    const float* xb = x + (size_t)b * NC * NPIX + n0;

    #pragma unroll
    for (int it = 0; it < 8; ++it) {
        int e = it * 256 + tid;
        int q  = e & 63;          // f4 col (4 pixels)
        int dp = e >> 6;          // d-pair 0..31
        f4 va = *(const f4*)(xb + (size_t)(2 * dp)     * NPIX + q * 4);
        f4 vb = *(const f4*)(xb + (size_t)(2 * dp + 1) * NPIX + q * 4);
        #pragma unroll
        for (int j = 0; j < 4; ++j) {
            float aj = (j == 0) ? va.x : (j == 1) ? va.y : (j == 2) ? va.z : va.w;
            float bj = (j == 0) ? vb.x : (j == 1) ? vb.y : (j == 2) ? vb.z : vb.w;
            *reinterpret_cast<unsigned int*>(&xT[(q * 4 + j) * XT_ROW + 2 * dp]) = pk(aj, bj);
        }
    }
    const float* Mb = M + b * 4096;
    #pragma unroll
    for (int it = 0; it < 4; ++it) {
        int e = it * 256 + tid;
        int c  = e >> 4;
        int qq = e & 15;
        f4 mv = *(const f4*)(Mb + c * 64 + qq * 4);
        *reinterpret_cast<unsigned int*>(&Ml[c * XT_ROW + qq * 4])     = pk(mv.x, mv.y);
        *reinterpret_cast<unsigned int*>(&Ml[c * XT_ROW + qq * 4 + 2]) = pk(mv.z, mv.w);
    }
    __syncthreads();

    const int w    = tid >> 6;
    const int lane = tid & 63;
    const int l15  = lane & 15;
    const int kh   = lane >> 4;

    h8 bfrag[4][2];
    #pragma unroll
    for (int nb = 0; nb < 4; ++nb)
        #pragma unroll
        for (int ks = 0; ks < 2; ++ks)
            bfrag[nb][ks] = *reinterpret_cast<const h8*>(
                &xT[(w * 64 + nb * 16 + l15) * XT_ROW + ks * 32 + kh * 8]);

    f4 acc[4][4];   // [cb][nb]
    #pragma unroll
    for (int cb = 0; cb < 4; ++cb)
        #pragma unroll
        for (int nb = 0; nb < 4; ++nb) acc[cb][nb] = (f4){0.f, 0.f, 0.f, 0.f};

    #pragma unroll
    for (int cb = 0; cb < 4; ++cb) {
        #pragma unroll
        for (int ks = 0; ks < 2; ++ks) {
            h8 a = *reinterpret_cast<const h8*>(
                &Ml[(cb * 16 + l15) * XT_ROW + ks * 32 + kh * 8]);
            #pragma unroll
            for (int nb = 0; nb < 4; ++nb)
                acc[cb][nb] = __builtin_amdgcn_mfma_f32_16x16x32_f16(a, bfrag[nb][ks], acc[cb][nb], 0, 0, 0);
        }
    }

    const size_t base = (size_t)b * NC * NPIX + n0 + w * 64;
    #pragma unroll
    for (int cb = 0; cb < 4; ++cb) {
        #pragma unroll
        for (int r = 0; r < 4; ++r) {
            const int row = cb * 16 + kh * 4 + r;
            #pragma unroll
            for (int nb = 0; nb < 4; ++nb) {
                size_t idx = base + (size_t)row * NPIX + nb * 16 + l15;
                out[idx] = acc[cb][nb][r] + x[idx];
            }
        }
    }
}

extern "C" void kernel_launch(void* const* d_in, const int* in_sizes, int n_in,
                              void* d_out, int out_size, void* d_ws, size_t ws_size,
                              hipStream_t stream) {
    const float* x     = (const float*)d_in[0];
    const float* g     = (const float*)d_in[1];
    const float* gamma = (const float*)d_in[2];
    float* out = (float*)d_out;
    float* ws  = (float*)d_ws;

    float* ex = ws;                  // 16*4096 floats
    float* eg = ws + NB * 4096;      // 16*4096 floats
    float* M  = ws + 2 * NB * 4096;  // 16*4096 floats

    // d_out doubles as scratch for the 33.5 MB gram partials; apply_kernel
    // fully overwrites d_out afterwards (stream-ordered), so this is safe.
    float* part = out;

    gram_kernel<<<dim3(NCHUNK, NB, 2), 256, 0, stream>>>(x, g, part);
    reduce_kernel<<<512, 256, 0, stream>>>(part, ex, eg);
    chain_kernel<<<NB, 256, 0, stream>>>(ex, eg, gamma, M);
    apply_kernel<<<dim3(NPIX / AP_NPX, NB), 256, 0, stream>>>(x, M, out);
}

// Round 10
// 272.299 us; speedup vs baseline: 1.0862x; 1.0386x over previous
//
#include <hip/hip_runtime.h>

// ---------------------------------------------------------------------------
// G_CAM_Module: out = gamma * (GA @ x) + x, where GA comes from a chain of
// softmaxed 64x64 Gram matrices of x and g.
//
//   A) gram_kernel  : partial Grams via MFMA f16, one matrix per block,
//                     17.5 KB LDS (8 blocks/CU). Staging loads all 8 float4
//                     into PINNED registers (batched issue -> 1 vmcnt drain
//                     per pass) before cvt+ds_write. R9's VGPR_Count=32
//                     showed the allocator had serialized the loads.
//   B) reduce_kernel: sum 64 chunk-partials -> ex[b], eg[b]
//   C) chain_kernel : softmax chain -> M = gamma*GA   (no identity; tiny fp32)
//   D) apply_kernel : out[b] = M[b] @ x_b + x_b via MFMA f16 (fp32 residual)
// ---------------------------------------------------------------------------

typedef _Float16 h8 __attribute__((ext_vector_type(8)));
typedef float    f4 __attribute__((ext_vector_type(4)));
typedef __fp16   p2 __attribute__((ext_vector_type(2)));   // cvt_pkrtz result
typedef unsigned long long ull;

#define NB 16
#define NC 64
#define NPIX 65536
#define GRAM_CHUNK 1024                 // pixels per gram block
#define PASS_PX 128                     // pixels per LDS pass
#define NPASS (GRAM_CHUNK / PASS_PX)    // 8
#define NCHUNK (NPIX / GRAM_CHUNK)      // 64
#define ROW_H 136                       // LDS row stride, halves (272 B)
#define LDS_H (64 * ROW_H + 64)         // halves incl. 8-row group pads

#define AP_NPX 256                      // apply: pixels per block
#define XT_ROW 72                       // apply: xT row stride in halves (144B)

__device__ __forceinline__ int rowbase_h(int c) {
    return c * ROW_H + (c >> 3) * 8;
}

__device__ __forceinline__ unsigned int pk(float a, float b) {
    p2 v = __builtin_amdgcn_cvt_pkrtz(a, b);
    return __builtin_bit_cast(unsigned int, v);
}

// ---- Kernel A: partial Gram matrices via MFMA, one matrix per block -------
// grid (64, 16, 2): chunk, batch, which-matrix. 256 threads = 4 waves; wave w
// computes the 16x64 slab rows [16w, 16w+16).
__global__ __launch_bounds__(256) void gram_kernel(
    const float* __restrict__ x, const float* __restrict__ g,
    float* __restrict__ part)
{
    __shared__ __align__(16) _Float16 buf[LDS_H];   // 17.5 KB

    const int tid = threadIdx.x;
    const int mtx = blockIdx.z;
    const float* src = (mtx ? g : x)
        + (size_t)blockIdx.y * NC * NPIX + (size_t)blockIdx.x * GRAM_CHUNK;

    const int w     = tid >> 6;
    const int lane  = tid & 63;
    const int l15   = lane & 15;
    const int khalf = lane >> 4;      // 0..3 -> 8-elem k-group
    const int abase_h = rowbase_h(w * 16 + l15);

    // staging coords: q = quad within 128 px; sr = base channel row (+8/it)
    const int sq = tid & 31;
    const int sr = tid >> 5;

    f4 acc[4];
    #pragma unroll
    for (int cb = 0; cb < 4; ++cb) acc[cb] = (f4){0.f, 0.f, 0.f, 0.f};

    for (int pass = 0; pass < NPASS; ++pass) {
        const float* ps = src + pass * PASS_PX;

        // ---- batched stage: issue ALL 8 float4 loads, pin results live ----
        float v0[4], v1[4], v2[4], v3[4], v4[4], v5[4], v6[4], v7[4];
        {
            f4 t;
            t = *(const f4*)(ps + (size_t)(0 * 8 + sr) * NPIX + sq * 4);
            v0[0] = t.x; v0[1] = t.y; v0[2] = t.z; v0[3] = t.w;
            t = *(const f4*)(ps + (size_t)(1 * 8 + sr) * NPIX + sq * 4);
            v1[0] = t.x; v1[1] = t.y; v1[2] = t.z; v1[3] = t.w;
            t = *(const f4*)(ps + (size_t)(2 * 8 + sr) * NPIX + sq * 4);
            v2[0] = t.x; v2[1] = t.y; v2[2] = t.z; v2[3] = t.w;
            t = *(const f4*)(ps + (size_t)(3 * 8 + sr) * NPIX + sq * 4);
            v3[0] = t.x; v3[1] = t.y; v3[2] = t.z; v3[3] = t.w;
            t = *(const f4*)(ps + (size_t)(4 * 8 + sr) * NPIX + sq * 4);
            v4[0] = t.x; v4[1] = t.y; v4[2] = t.z; v4[3] = t.w;
            t = *(const f4*)(ps + (size_t)(5 * 8 + sr) * NPIX + sq * 4);
            v5[0] = t.x; v5[1] = t.y; v5[2] = t.z; v5[3] = t.w;
            t = *(const f4*)(ps + (size_t)(6 * 8 + sr) * NPIX + sq * 4);
            v6[0] = t.x; v6[1] = t.y; v6[2] = t.z; v6[3] = t.w;
            t = *(const f4*)(ps + (size_t)(7 * 8 + sr) * NPIX + sq * 4);
            v7[0] = t.x; v7[1] = t.y; v7[2] = t.z; v7[3] = t.w;
        }
        // pin: forces all 8 loads' results into live VGPRs (no per-element
        // load->use serialization; loads cluster, single vmcnt drain)
        #pragma unroll
        for (int j = 0; j < 4; ++j) {
            asm volatile("" : "+v"(v0[j]), "+v"(v1[j]), "+v"(v2[j]), "+v"(v3[j]));
            asm volatile("" : "+v"(v4[j]), "+v"(v5[j]), "+v"(v6[j]), "+v"(v7[j]));
        }

        // ---- cvt + LDS write ----
        {
            ull h;
            h = (ull)pk(v0[0], v0[1]) | ((ull)pk(v0[2], v0[3]) << 32);
            *reinterpret_cast<ull*>(&buf[rowbase_h(0 * 8 + sr) + 4 * sq]) = h;
            h = (ull)pk(v1[0], v1[1]) | ((ull)pk(v1[2], v1[3]) << 32);
            *reinterpret_cast<ull*>(&buf[rowbase_h(1 * 8 + sr) + 4 * sq]) = h;
            h = (ull)pk(v2[0], v2[1]) | ((ull)pk(v2[2], v2[3]) << 32);
            *reinterpret_cast<ull*>(&buf[rowbase_h(2 * 8 + sr) + 4 * sq]) = h;
            h = (ull)pk(v3[0], v3[1]) | ((ull)pk(v3[2], v3[3]) << 32);
            *reinterpret_cast<ull*>(&buf[rowbase_h(3 * 8 + sr) + 4 * sq]) = h;
            h = (ull)pk(v4[0], v4[1]) | ((ull)pk(v4[2], v4[3]) << 32);
            *reinterpret_cast<ull*>(&buf[rowbase_h(4 * 8 + sr) + 4 * sq]) = h;
            h = (ull)pk(v5[0], v5[1]) | ((ull)pk(v5[2], v5[3]) << 32);
            *reinterpret_cast<ull*>(&buf[rowbase_h(5 * 8 + sr) + 4 * sq]) = h;
            h = (ull)pk(v6[0], v6[1]) | ((ull)pk(v6[2], v6[3]) << 32);
            *reinterpret_cast<ull*>(&buf[rowbase_h(6 * 8 + sr) + 4 * sq]) = h;
            h = (ull)pk(v7[0], v7[1]) | ((ull)pk(v7[2], v7[3]) << 32);
            *reinterpret_cast<ull*>(&buf[rowbase_h(7 * 8 + sr) + 4 * sq]) = h;
        }
        __syncthreads();

        // ---- consume: 4 K-steps x (1 A-frag + 4 B-frags + 4 MFMA) ----
        #pragma unroll
        for (int ks = 0; ks < 4; ++ks) {
            int koff = ks * 32 + khalf * 8;
            h8 a = *reinterpret_cast<const h8*>(&buf[abase_h + koff]);
            #pragma unroll
            for (int cb = 0; cb < 4; ++cb) {
                h8 bf = *reinterpret_cast<const h8*>(&buf[rowbase_h(cb * 16 + l15) + koff]);
                acc[cb] = __builtin_amdgcn_mfma_f32_16x16x32_f16(a, bf, acc[cb], 0, 0, 0);
            }
        }
        __syncthreads();
    }

    float* po = part + (((size_t)blockIdx.x * NB + blockIdx.y) * 2 + mtx) * 4096;
    #pragma unroll
    for (int cb = 0; cb < 4; ++cb)
        #pragma unroll
        for (int r = 0; r < 4; ++r)
            po[(w * 16 + khalf * 4 + r) * 64 + cb * 16 + l15] = acc[cb][r];
}

// ---- Kernel B: reduce 64 chunk-partials -> ex, eg -------------------------
__global__ __launch_bounds__(256) void reduce_kernel(
    const float* __restrict__ part, float* __restrict__ ex, float* __restrict__ eg)
{
    const int idx = blockIdx.x * 256 + threadIdx.x;
    const int bm = idx >> 12;          // b*2 + m
    const int cd = idx & 4095;
    float s = 0.f;
    #pragma unroll 8
    for (int ch = 0; ch < NCHUNK; ++ch)
        s += part[(size_t)ch * (NB * 2 * 4096) + (size_t)bm * 4096 + cd];
    float* dst = (bm & 1) ? eg : ex;
    dst[(bm >> 1) * 4096 + cd] = s;
}

// ---- Kernel C: softmax chain -> M = gamma*GA (no identity) ----------------
__global__ __launch_bounds__(256) void chain_kernel(
    const float* __restrict__ ex, const float* __restrict__ eg,
    const float* __restrict__ gammap, float* __restrict__ M)
{
    __shared__ float A1[64][68];
    __shared__ float A2[64][68];
    __shared__ float red[64][4];

    const int b = blockIdx.x;
    const int tid = threadIdx.x;

    if (tid < 64) {
        const int c = tid;
        float r[64];
        #pragma unroll
        for (int d = 0; d < 64; ++d) r[d] = ex[b * 4096 + c * 64 + d];
        float mx = r[0];
        #pragma unroll
        for (int d = 1; d < 64; ++d) mx = fmaxf(mx, r[d]);
        float s = 0.f;
        #pragma unroll
        for (int d = 0; d < 64; ++d) { r[d] = expf(r[d] - mx); s += r[d]; }
        float inv = 1.f / s;
        #pragma unroll
        for (int d = 0; d < 64; ++d) A1[c][d] = r[d] * inv;

        #pragma unroll
        for (int d = 0; d < 64; ++d) r[d] = eg[b * 4096 + c * 64 + d];
        mx = r[0];
        #pragma unroll
        for (int d = 1; d < 64; ++d) mx = fmaxf(mx, r[d]);
        s = 0.f;
        #pragma unroll
        for (int d = 0; d < 64; ++d) { r[d] = expf(r[d] - mx); s += r[d]; }
        inv = 1.f / s;
        #pragma unroll
        for (int d = 0; d < 64; ++d) A2[c][d] = r[d] * inv;
    }
    __syncthreads();

    const int c = tid >> 2, sq = tid & 3;
    float ge[16];
    #pragma unroll
    for (int k = 0; k < 16; ++k) ge[k] = 0.f;
    for (int d = 0; d < 64; ++d) {
        float a = A1[c][d];
        const float* row = &A2[d][sq * 16];
        #pragma unroll
        for (int k = 0; k < 16; ++k) ge[k] = fmaf(a, row[k], ge[k]);
    }

    float mx = ge[0];
    #pragma unroll
    for (int k = 1; k < 16; ++k) mx = fmaxf(mx, ge[k]);
    red[c][sq] = mx;
    __syncthreads();
    float gm = fmaxf(fmaxf(red[c][0], red[c][1]), fmaxf(red[c][2], red[c][3]));
    __syncthreads();

    float gen[16];
    #pragma unroll
    for (int k = 0; k < 16; ++k) gen[k] = gm - ge[k];
    float mx2 = gen[0];
    #pragma unroll
    for (int k = 1; k < 16; ++k) mx2 = fmaxf(mx2, gen[k]);
    red[c][sq] = mx2;
    __syncthreads();
    float m2 = fmaxf(fmaxf(red[c][0], red[c][1]), fmaxf(red[c][2], red[c][3]));
    __syncthreads();

    float p[16];
    float s = 0.f;
    #pragma unroll
    for (int k = 0; k < 16; ++k) { p[k] = expf(gen[k] - m2); s += p[k]; }
    red[c][sq] = s;
    __syncthreads();
    float S = red[c][0] + red[c][1] + red[c][2] + red[c][3];

    float gam = gammap[0];
    float invS = 1.f / S;
    #pragma unroll
    for (int k = 0; k < 16; ++k) {
        int e = sq * 16 + k;
        M[b * 4096 + c * 64 + e] = gam * p[k] * invS;   // NO +I: residual in apply
    }
}

// ---- Kernel D: out[b] = M[b] @ x[b] + x[b] via MFMA ------------------------
__global__ __launch_bounds__(256) void apply_kernel(
    const float* __restrict__ x, const float* __restrict__ M,
    float* __restrict__ out)
{
    __shared__ __align__(16) _Float16 xT[AP_NPX * XT_ROW];   // 36864 B
    __shared__ __align__(16) _Float16 Ml[64 * XT_ROW];       //  9216 B

    const int tid = threadIdx.x;
    const int b = blockIdx.y;
    const int n0 = blockIdx.x * AP_NPX;
    const float* xb = x + (size_t)b * NC * NPIX + n0;

    #pragma unroll
    for (int it = 0; it < 8; ++it) {
        int e = it * 256 + tid;
        int q  = e & 63;          // f4 col (4 pixels)
        int dp = e >> 6;          // d-pair 0..31
        f4 va = *(const f4*)(xb + (size_t)(2 * dp)     * NPIX + q * 4);
        f4 vb = *(const f4*)(xb + (size_t)(2 * dp + 1) * NPIX + q * 4);
        #pragma unroll
        for (int j = 0; j < 4; ++j) {
            float aj = (j == 0) ? va.x : (j == 1) ? va.y : (j == 2) ? va.z : va.w;
            float bj = (j == 0) ? vb.x : (j == 1) ? vb.y : (j == 2) ? vb.z : vb.w;
            *reinterpret_cast<unsigned int*>(&xT[(q * 4 + j) * XT_ROW + 2 * dp]) = pk(aj, bj);
        }
    }
    const float* Mb = M + b * 4096;
    #pragma unroll
    for (int it = 0; it < 4; ++it) {
        int e = it * 256 + tid;
        int c  = e >> 4;
        int qq = e & 15;
        f4 mv = *(const f4*)(Mb + c * 64 + qq * 4);
        *reinterpret_cast<unsigned int*>(&Ml[c * XT_ROW + qq * 4])     = pk(mv.x, mv.y);
        *reinterpret_cast<unsigned int*>(&Ml[c * XT_ROW + qq * 4 + 2]) = pk(mv.z, mv.w);
    }
    __syncthreads();

    const int w    = tid >> 6;
    const int lane = tid & 63;
    const int l15  = lane & 15;
    const int kh   = lane >> 4;

    h8 bfrag[4][2];
    #pragma unroll
    for (int nb = 0; nb < 4; ++nb)
        #pragma unroll
        for (int ks = 0; ks < 2; ++ks)
            bfrag[nb][ks] = *reinterpret_cast<const h8*>(
                &xT[(w * 64 + nb * 16 + l15) * XT_ROW + ks * 32 + kh * 8]);

    f4 acc[4][4];   // [cb][nb]
    #pragma unroll
    for (int cb = 0; cb < 4; ++cb)
        #pragma unroll
        for (int nb = 0; nb < 4; ++nb) acc[cb][nb] = (f4){0.f, 0.f, 0.f, 0.f};

    #pragma unroll
    for (int cb = 0; cb < 4; ++cb) {
        #pragma unroll
        for (int ks = 0; ks < 2; ++ks) {
            h8 a = *reinterpret_cast<const h8*>(
                &Ml[(cb * 16 + l15) * XT_ROW + ks * 32 + kh * 8]);
            #pragma unroll
            for (int nb = 0; nb < 4; ++nb)
                acc[cb][nb] = __builtin_amdgcn_mfma_f32_16x16x32_f16(a, bfrag[nb][ks], acc[cb][nb], 0, 0, 0);
        }
    }

    const size_t base = (size_t)b * NC * NPIX + n0 + w * 64;
    #pragma unroll
    for (int cb = 0; cb < 4; ++cb) {
        #pragma unroll
        for (int r = 0; r < 4; ++r) {
            const int row = cb * 16 + kh * 4 + r;
            #pragma unroll
            for (int nb = 0; nb < 4; ++nb) {
                size_t idx = base + (size_t)row * NPIX + nb * 16 + l15;
                out[idx] = acc[cb][nb][r] + x[idx];
            }
        }
    }
}

extern "C" void kernel_launch(void* const* d_in, const int* in_sizes, int n_in,
                              void* d_out, int out_size, void* d_ws, size_t ws_size,
                              hipStream_t stream) {
    const float* x     = (const float*)d_in[0];
    const float* g     = (const float*)d_in[1];
    const float* gamma = (const float*)d_in[2];
    float* out = (float*)d_out;
    float* ws  = (float*)d_ws;

    float* ex = ws;                  // 16*4096 floats
    float* eg = ws + NB * 4096;      // 16*4096 floats
    float* M  = ws + 2 * NB * 4096;  // 16*4096 floats

    // d_out doubles as scratch for the 33.5 MB gram partials; apply_kernel
    // fully overwrites d_out afterwards (stream-ordered), so this is safe.
    float* part = out;

    gram_kernel<<<dim3(NCHUNK, NB, 2), 256, 0, stream>>>(x, g, part);
    reduce_kernel<<<512, 256, 0, stream>>>(part, ex, eg);
    chain_kernel<<<NB, 256, 0, stream>>>(ex, eg, gamma, M);
    apply_kernel<<<dim3(NPIX / AP_NPX, NB), 256, 0, stream>>>(x, M, out);
}